// Round 1
// 93.722 us; speedup vs baseline: 1.0830x; 1.0830x over previous
//
#include <hip/hip_runtime.h>
#include <math.h>

#define LATN 721
#define LONN 1440
#define NLEV 13
#define NBATCH 2
#define SLICE (LATN * LONN)              // 1,038,240
#define BATSTRIDE (NLEV * SLICE)

// fused-tile geometry
#define TI 8
#define TJ 32
#define HR (TI + 2)                      // 10 halo rows
#define HC (TJ + 2)                      // 34 halo cols
#define NRT 91                           // ceil(721/8)
#define NCT 45                           // 1440/32
#define NWG (NRT * NCT)                  // 4095

// ---- ws float layout ----
// Banked accumulators: 128 banks x 64 floats (each bank = its own cache lines)
#define NBANK      128
#define BANKSTRIDE 64
#define WS_ACC     0                     // [NBANK*BANKSTRIDE]
#define ACC_SUM    0        // [26] per (b,l) sums
#define ACC_SSQ    26       // [2]  per-batch total sum-of-squares (collapsed over l)
#define ACC_GRAD   28
#define ACC_MASS   29
#define N_ACC      30
#define WS_INVDX   (NBANK * BANKSTRIDE)          // [721]
#define WS_FCOR    (WS_INVDX + LATN)             // [721]
#define WS_W       (WS_FCOR + LATN)              // [13]
#define WS_INVDP   (WS_W + NLEV)
#define WS_INV2DP  (WS_INVDP + 1)

constexpr float INV_R     = (float)(1.0 / 6371000.0);
constexpr float INV_DLAT  = (float)(720.0 / M_PI);
constexpr float INV_2DLAT = (float)(360.0 / M_PI);
constexpr float INV_DLON  = (float)(1440.0 / (2.0 * M_PI));
constexpr float INV_2DLON = (float)(720.0 / (2.0 * M_PI));
constexpr float QG_COEF   = 1e-4f;   // F0^2 / N^2

// ---------------- setup: row tables, weights, zero accumulators ----------------
__global__ void pl_setup_kernel(const float* __restrict__ plev, float* __restrict__ ws) {
    const int t = threadIdx.x;
    if (t < LATN) {
        double lat;
        if (t == 0)            lat = (double)(-(float)(M_PI / 2.0));
        else if (t == LATN-1)  lat = (double)( (float)(M_PI / 2.0));
        else                   lat = (double)((float)(-M_PI / 2.0 + (double)t * (M_PI / 720.0)));
        double c = cos(lat);
        if (c < 1e-8) c = 1e-8;                      // matches jnp.clip(cos, 1e-8)
        ws[WS_INVDX + t] = (float)(1.0 / (6371000.0 * c));
        ws[WS_FCOR  + t] = (float)(2.0 * 7.292e-05 * sin(lat));
    }
    if (t < NLEV) {
        float p[NLEV];
        #pragma unroll
        for (int l = 0; l < NLEV; ++l) p[l] = plev[l] * 100.0f;
        float dpl[NLEV-1];
        #pragma unroll
        for (int l = 0; l < NLEV-1; ++l) dpl[l] = p[l+1] - p[l];
        float raw;
        if (t == 0)            raw = dpl[0] * 0.5f;
        else if (t == NLEV-1)  raw = dpl[NLEV-2] * 0.5f;
        else                   raw = (dpl[t-1] + dpl[t]) * 0.5f;
        float s = dpl[0] * 0.5f + dpl[NLEV-2] * 0.5f;
        #pragma unroll
        for (int l = 1; l < NLEV-1; ++l) s += (dpl[l-1] + dpl[l]) * 0.5f;
        if (s < 1e-8f) s = 1e-8f;
        ws[WS_W + t] = raw / s;
    }
    if (t == 0) {
        float sd = 0.f;
        for (int l = 0; l < NLEV-1; ++l) sd += plev[l+1] - plev[l];
        float dp = sd / (float)(NLEV-1) * 100.0f;    // mean(diff)*100 (hPa->Pa)
        ws[WS_INVDP]  = 1.0f / dp;
        ws[WS_INV2DP] = 1.0f / (2.0f * dp);
    }
    for (int z = t; z < NBANK * BANKSTRIDE; z += 1024) ws[WS_ACC + z] = 0.0f;
}

// ---------------- helpers ----------------
__device__ __forceinline__ int swz_nwg(int orig, int nwg) {
    // bijective XCD-chunk swizzle (m204)
    const int q = nwg >> 3, r = nwg & 7;
    const int x = orig & 7, k = orig >> 3;
    return (x < r ? x * (q + 1) : r * (q + 1) + (x - r) * q) + k;
}

// ---------------- fused kernel: qg + weighted-column U,V in LDS, one pass ----------------
__launch_bounds__(256)
__global__ void pl_fused_kernel(const float* __restrict__ u, const float* __restrict__ v,
                                float* __restrict__ ws)
{
    __shared__ float qg[NLEV * HR * HC];     // 17,680 B
    __shared__ float Ucol[HR * HC];          // weighted column sum of u (mass-div linearity)
    __shared__ float Vcol[HR * HC];          // weighted column sum of v
    __shared__ float red[16][17];

    const int b  = blockIdx.y;
    const int wg = swz_nwg(blockIdx.x, NWG);
    const int rt = wg / NCT, ct = wg - rt * NCT;
    const int i0 = rt * TI, j0 = ct * TJ;

    const float* ub = u + (size_t)b * BATSTRIDE;
    const float* vb = v + (size_t)b * BATSTRIDE;
    const float idp = ws[WS_INVDP], i2dp = ws[WS_INV2DP];

    float wlev[NLEV];                        // uniform -> SGPRs
    #pragma unroll
    for (int l = 0; l < NLEV; ++l) wlev[l] = ws[WS_W + l];

    // ---- phase 1: qg + U,V for halo region into LDS (the ONLY global loads) ----
    for (int hidx = threadIdx.x; hidx < HR * HC; hidx += 256) {
        const int hr = hidx / HC, hc = hidx - hr * HC;
        int r = i0 - 1 + hr; r = max(0, min(r, LATN - 1));
        int c = j0 - 1 + hc; c = max(0, min(c, LONN - 1));
        const int ro  = r * LONN;
        const int rpo = min(r + 1, LATN - 1) * LONN;
        const int rmo = max(r - 1, 0) * LONN;
        const int cp  = min(c + 1, LONN - 1);
        const int cm  = max(c - 1, 0);
        const float sc = ((c == 0 || c == LONN - 1) ? INV_DLON : INV_2DLON) * ws[WS_INVDX + r];
        const float sr = ((r == 0 || r == LATN - 1) ? INV_DLAT : INV_2DLAT) * INV_R;
        const float fc = ws[WS_FCOR + r];

        float vo[NLEV];
        float wu = 0.f, wv = 0.f;
        #pragma unroll
        for (int l = 0; l < NLEV; ++l) {
            const size_t o = (size_t)l * SLICE;
            vo[l] = (vb[o + ro + cp] - vb[o + ro + cm]) * sc
                  - (ub[o + rpo + c] - ub[o + rmo + c]) * sr;
            wu = fmaf(wlev[l], ub[o + ro + c], wu);
            wv = fmaf(wlev[l], vb[o + ro + c], wv);
        }
        Ucol[hidx] = wu;
        Vcol[hidx] = wv;

        // hoisted first vertical derivative (computed once, not 3x per level)
        float vp1[NLEV];
        vp1[0]        = (vo[1] - vo[0]) * idp;
        #pragma unroll
        for (int l = 1; l < NLEV - 1; ++l) vp1[l] = (vo[l+1] - vo[l-1]) * i2dp;
        vp1[NLEV-1]   = (vo[NLEV-1] - vo[NLEV-2]) * idp;
        #pragma unroll
        for (int l = 0; l < NLEV; ++l) {
            float vpp;
            if (l == 0)             vpp = (vp1[1] - vp1[0]) * idp;
            else if (l == NLEV - 1) vpp = (vp1[NLEV-1] - vp1[NLEV-2]) * idp;
            else                    vpp = (vp1[l+1] - vp1[l-1]) * i2dp;
            qg[l * (HR * HC) + hidx] = vo[l] + fc + QG_COEF * vpp;
        }
    }
    __syncthreads();

    // ---- phase 2: pure-LDS stencils, zero global traffic ----
    const int oi = threadIdx.x >> 5, oj = threadIdx.x & 31;
    const int i = i0 + oi, j = j0 + oj;
    const float mval = (i < LATN) ? 1.f : 0.f;
    const int ic = min(i, LATN - 1);
    const int hb = (oi + 1) * HC + (oj + 1);
    const float siR = ((ic == 0 || ic == LATN - 1) ? INV_DLAT : INV_2DLAT) * INV_R;
    const float sjx = ((j == 0 || j == LONN - 1) ? INV_DLON : INV_2DLON) * ws[WS_INVDX + ic];

    float vals[16];
    float ssqt = 0.f, grad = 0.f;
    #pragma unroll
    for (int l = 0; l < NLEV; ++l) {
        const int base = l * HR * HC + hb;
        const float qc = qg[base];
        const float gl = (qg[base + HC] - qg[base - HC]) * siR;
        const float gn = (qg[base + 1]  - qg[base - 1])  * sjx;
        vals[l] = qc;
        ssqt += qc * qc;
        grad += gl * gl + gn * gn;
    }
    const float du = (Ucol[hb + 1]  - Ucol[hb - 1])  * sjx;
    const float dv = (Vcol[hb + HC] - Vcol[hb - HC]) * siR;
    const float cd = du + dv;
    vals[13] = ssqt;
    vals[14] = grad;
    vals[15] = cd * cd;

    // ---- reduction: 4-step 16-lane-group butterfly + LDS transpose (16 values) ----
    #pragma unroll
    for (int k = 0; k < 16; ++k) {
        float x = vals[k] * mval;
        x += __shfl_xor(x, 8, 64);
        x += __shfl_xor(x, 4, 64);
        x += __shfl_xor(x, 2, 64);
        x += __shfl_xor(x, 1, 64);
        vals[k] = x;   // every lane in an aligned 16-group now holds all 16 group sums
    }
    const int g = threadIdx.x >> 4, k16 = threadIdx.x & 15;
    float myv = vals[0];
    #pragma unroll
    for (int k = 1; k < 16; ++k) if (k16 == k) myv = vals[k];   // static-index select (no scratch)
    red[g][k16] = myv;
    __syncthreads();

    if (threadIdx.x < 16) {
        const int k = threadIdx.x;
        float s = 0.f;
        #pragma unroll
        for (int g2 = 0; g2 < 16; ++g2) s += red[g2][k];
        int target;
        if (k < 13)       target = ACC_SUM + b * 13 + k;
        else if (k == 13) target = ACC_SSQ + b;
        else if (k == 14) target = ACC_GRAD;
        else              target = ACC_MASS;
        const int bank = (b * NWG + blockIdx.x) & (NBANK - 1);
        atomicAdd(&ws[WS_ACC + bank * BANKSTRIDE + target], s);
    }
}

// ---------------- finalize: sum banks, apply formulas ----------------
__global__ void pl_finalize_kernel(const float* __restrict__ ws, float* __restrict__ out) {
    __shared__ float tot[N_ACC];
    const int t = threadIdx.x;
    if (t < N_ACC) {
        float s = 0.f;
        for (int bk = 0; bk < NBANK; ++bk) s += ws[WS_ACC + bk * BANKSTRIDE + t];
        tot[t] = s;
    }
    __syncthreads();
    if (t == 0) {
        const float N = (float)SLICE;
        float s2 = 0.f;
        for (int s = 0; s < 2 * NLEV; ++s) s2 += tot[ACC_SUM + s] * tot[ACC_SUM + s];
        const float ssq = tot[ACC_SSQ + 0] + tot[ACC_SSQ + 1];
        // sum over (b,l) of (ssq_bl - sum_bl^2/N)/(N-1), then /26 — ssq collapsed by linearity
        float vmean = (ssq - s2 / N) / (N - 1.0f) * (1.0f / (2.0f * NLEV));
        float gmean = tot[ACC_GRAD] / (float)(NBATCH * NLEV * SLICE);
        float mmean = tot[ACC_MASS] / (float)(NBATCH * SLICE);
        out[0] = vmean + 0.1f * gmean + mmean;          // spectra_loss statically 0
    }
}

extern "C" void kernel_launch(void* const* d_in, const int* in_sizes, int n_in,
                              void* d_out, int out_size, void* d_ws, size_t ws_size,
                              hipStream_t stream) {
    const float* u    = (const float*)d_in[0];
    const float* v    = (const float*)d_in[1];
    const float* plev = (const float*)d_in[2];
    float* ws  = (float*)d_ws;
    float* out = (float*)d_out;

    hipLaunchKernelGGL(pl_setup_kernel, dim3(1), dim3(1024), 0, stream, plev, ws);
    hipLaunchKernelGGL(pl_fused_kernel, dim3(NWG, NBATCH), dim3(256), 0, stream, u, v, ws);
    hipLaunchKernelGGL(pl_finalize_kernel, dim3(1), dim3(64), 0, stream, ws, out);
}